// Round 1
// baseline (317.368 us; speedup 1.0000x reference)
//
#include <hip/hip_runtime.h>
#include <hip/hip_bf16.h>

#define D 128
#define CH 4096   // edges per block in CSR partition passes
#define BM 64     // gemm rows per block

typedef unsigned int u32;
typedef unsigned short u16;
typedef __attribute__((ext_vector_type(8))) short s16x8;
typedef __attribute__((ext_vector_type(4))) float f32x4;
typedef __attribute__((ext_vector_type(2))) float f32x2;

__device__ __forceinline__ float bf2f(u16 u) {
    union { u32 u; float f; } v; v.u = ((u32)u) << 16; return v.f;
}
__device__ __forceinline__ u16 f2bf(float f) {
    union { float f; u32 u; } v; v.f = f;
    return (u16)((v.u + 0x7fffu + ((v.u >> 16) & 1u)) >> 16);
}
__device__ __forceinline__ u32 pack_bf2(float a, float b) {
    __hip_bfloat162 t = __float22bfloat162_rn(make_float2(a, b));
    union { __hip_bfloat162 t; u32 u; } v; v.t = t; return v.u;
}
__device__ __forceinline__ void unpack2(u32 u, float& lo, float& hi) {
    union { u32 u; float f; } a, b;
    a.u = u << 16; b.u = u & 0xffff0000u;
    lo = a.f; hi = b.f;
}

// ---- dtype detector (also zeroes gcnt for the CSR build) ----
__global__ void detect_dtype(const u16* __restrict__ x, int* __restrict__ flag,
                             int* __restrict__ gcnt, int nbuck) {
    __shared__ int cnt;
    if (threadIdx.x == 0) cnt = 0;
    __syncthreads();
    if ((int)threadIdx.x < nbuck) gcnt[threadIdx.x] = 0;
    u16 u = x[2 * threadIdx.x];
    int e = (u >> 7) & 0xFF;
    if (e >= 96 && e <= 150) atomicAdd(&cnt, 1);
    __syncthreads();
    if (threadIdx.x == 0) *flag = (cnt >= 128) ? 0 : 1;
}

// ---- canonicalize (body only runs when inputs are fp32) ----
__global__ __launch_bounds__(256)
void to_bf16_all(const void* __restrict__ s0, const void* __restrict__ s1,
                 const void* __restrict__ s2, const void* __restrict__ s3,
                 const void* __restrict__ s4, const void* __restrict__ s5,
                 const void* __restrict__ s6,
                 u16* __restrict__ d0, u16* __restrict__ d1, u16* __restrict__ d2,
                 u16* __restrict__ d3, u16* __restrict__ d4, u16* __restrict__ d5,
                 u16* __restrict__ d6,
                 long long n0, long long n1, long long n2, long long n3,
                 long long n4, long long n5, long long n6,
                 const int* __restrict__ flag)
{
    if (*flag == 0) return;
    long long i = (long long)blockIdx.x * 256 + threadIdx.x;
    const void* s; u16* d; long long off;
    if      (i < n0)                   { s = s0; d = d0; off = i; }
    else if (i < n0+n1)                { s = s1; d = d1; off = i-n0; }
    else if (i < n0+n1+n2)             { s = s2; d = d2; off = i-n0-n1; }
    else if (i < n0+n1+n2+n3)          { s = s3; d = d3; off = i-n0-n1-n2; }
    else if (i < n0+n1+n2+n3+n4)       { s = s4; d = d4; off = i-n0-n1-n2-n3; }
    else if (i < n0+n1+n2+n3+n4+n5)    { s = s5; d = d5; off = i-n0-n1-n2-n3-n4; }
    else if (i < n0+n1+n2+n3+n4+n5+n6) { s = s6; d = d6; off = i-n0-n1-n2-n3-n4-n5; }
    else return;
    d[off] = f2bf(((const float*)s)[off]);
}

// ==== bucketed CSR build: bucket = dst>>8 (needs N<=65536, src<2^16) ====
__global__ __launch_bounds__(256)
void csr_count(const int* __restrict__ dst, int* __restrict__ gcnt, int E, int nbuck) {
    __shared__ int scnt[256];
    int tid = threadIdx.x;
    scnt[tid] = 0;
    __syncthreads();
    int base = blockIdx.x * CH;
#pragma unroll
    for (int it = 0; it < CH / 256; ++it) {
        int e = base + it * 256 + tid;
        if (e < E) atomicAdd(&scnt[dst[e] >> 8], 1);
    }
    __syncthreads();
    if (tid < nbuck && scnt[tid] > 0) atomicAdd(&gcnt[tid], scnt[tid]);
}

__global__ __launch_bounds__(256)
void csr_scan(const int* __restrict__ gcnt, int* __restrict__ bstart, int* __restrict__ bcur,
              int nbuck, int N_, int E_, int* __restrict__ offs) {
    __shared__ int wpart[4];
    int tid = threadIdx.x, lane = tid & 63, wid = tid >> 6;
    int v = (tid < nbuck) ? gcnt[tid] : 0;
    int s = v;
#pragma unroll
    for (int off = 1; off < 64; off <<= 1) {
        int t = __shfl_up(s, off, 64);
        if (lane >= off) s += t;
    }
    if (lane == 63) wpart[wid] = s;
    __syncthreads();
    int add = 0;
    for (int w = 0; w < wid; ++w) add += wpart[w];
    int excl = add + s - v;
    if (tid <= nbuck) bstart[tid] = excl;
    if (tid < nbuck)  bcur[tid]  = excl;
    if (tid == 0) offs[N_] = E_;
}

// partition edges into bucket-contiguous ebuf; rec = (dst&255)<<24 | (et<<16) | src
__global__ __launch_bounds__(256)
void csr_part(const int* __restrict__ src, const int* __restrict__ dst,
              const int* __restrict__ et, int* __restrict__ bcur,
              u32* __restrict__ ebuf, int E, int N, int nbuck) {
    __shared__ int scnt[256], sbase[256];
    int tid = threadIdx.x;
    scnt[tid] = 0;
    __syncthreads();
    int base = blockIdx.x * CH;
#pragma unroll
    for (int it = 0; it < CH / 256; ++it) {
        int e = base + it * 256 + tid;
        if (e < E) atomicAdd(&scnt[dst[e] >> 8], 1);
    }
    __syncthreads();
    if (tid < nbuck) {
        int c = scnt[tid];
        sbase[tid] = c ? atomicAdd(&bcur[tid], c) : 0;
    }
    __syncthreads();
    scnt[tid] = 0;
    __syncthreads();
#pragma unroll
    for (int it = 0; it < CH / 256; ++it) {
        int e = base + it * 256 + tid;
        if (e >= E) continue;
        int d = dst[e];
        int b = d >> 8;
        int p = sbase[b] + atomicAdd(&scnt[b], 1);
        ebuf[p] = ((u32)(d & 255) << 24) | ((u32)et[e] << 16) | (u32)src[e];
    }
}

// one block per bucket: 256-bin dstlo counting sort -> offs + rowidx ((et<<16)|src)
__global__ __launch_bounds__(256)
void csr_emit(const u32* __restrict__ ebuf, const int* __restrict__ bstart,
              int* __restrict__ offs, int* __restrict__ rowidx, int N) {
    __shared__ int hist[256], excl[256], cur[256];
    __shared__ int wpart[4];
    int b = blockIdx.x, tid = threadIdx.x;
    int lo = bstart[b], hi = bstart[b + 1];
    hist[tid] = 0; cur[tid] = 0;
    __syncthreads();
    for (int i = lo + tid; i < hi; i += 256) atomicAdd(&hist[ebuf[i] >> 24], 1);
    __syncthreads();
    int lane = tid & 63, wid = tid >> 6;
    int v = hist[tid], s = v;
#pragma unroll
    for (int off = 1; off < 64; off <<= 1) {
        int t = __shfl_up(s, off, 64);
        if (lane >= off) s += t;
    }
    if (lane == 63) wpart[wid] = s;
    __syncthreads();
    int add = 0;
    for (int w = 0; w < wid; ++w) add += wpart[w];
    int e_ = add + s - v;
    excl[tid] = e_;
    int node = (b << 8) + tid;
    if (node < N) offs[node] = lo + e_;
    __syncthreads();
    for (int i = lo + tid; i < hi; i += 256) {
        u32 rec = ebuf[i];
        int dl = rec >> 24;
        int p = lo + excl[dl] + atomicAdd(&cur[dl], 1);
        rowidx[p] = (int)(rec & 0xFFFFFFu);
    }
}

// ---- agg_pre: input-space aggregation. s[r][v][:] = sum over in-edges of type r of x[src].
// One wave per dst node; lane p holds features 2p, 2p+1 for all 8 relations (16 f32 accs).
// Gather source is the 12.8 MB x/h table (LLC-resident) instead of the 102 MB xw table.
#define ACC8(et_, u_) do { float l_, h_; unpack2((u_), l_, h_);        \
    switch (et_) {                                                     \
    case 0: aL[0] += l_; aH[0] += h_; break;                           \
    case 1: aL[1] += l_; aH[1] += h_; break;                           \
    case 2: aL[2] += l_; aH[2] += h_; break;                           \
    case 3: aL[3] += l_; aH[3] += h_; break;                           \
    case 4: aL[4] += l_; aH[4] += h_; break;                           \
    case 5: aL[5] += l_; aH[5] += h_; break;                           \
    case 6: aL[6] += l_; aH[6] += h_; break;                           \
    default: aL[7] += l_; aH[7] += h_; break; } } while (0)

__global__ __launch_bounds__(256)
void agg_pre(const u16* __restrict__ xc, const u16* __restrict__ xo,
             const int* __restrict__ offs, const int* __restrict__ rowidx,
             u16* __restrict__ s, int N_, int R_, const int* __restrict__ flag)
{
    const u16* x = (*flag != 0) ? xc : xo;
    int node = blockIdx.x * 4 + (threadIdx.x >> 6);
    int lane = threadIdx.x & 63;
    if (node >= N_) return;
    const u32* xr = (const u32*)x;   // row stride = 64 u32

    float aL[8] = {0.f,0.f,0.f,0.f,0.f,0.f,0.f,0.f};
    float aH[8] = {0.f,0.f,0.f,0.f,0.f,0.f,0.f,0.f};

    int j  = __builtin_amdgcn_readfirstlane(offs[node]);
    int j1 = __builtin_amdgcn_readfirstlane(offs[node + 1]);

    for (; j + 4 <= j1; j += 4) {
        int v0 = __builtin_amdgcn_readfirstlane(rowidx[j + 0]);
        int v1 = __builtin_amdgcn_readfirstlane(rowidx[j + 1]);
        int v2 = __builtin_amdgcn_readfirstlane(rowidx[j + 2]);
        int v3 = __builtin_amdgcn_readfirstlane(rowidx[j + 3]);
        u32 u0 = xr[(size_t)(v0 & 0xffff) * 64 + lane];
        u32 u1 = xr[(size_t)(v1 & 0xffff) * 64 + lane];
        u32 u2 = xr[(size_t)(v2 & 0xffff) * 64 + lane];
        u32 u3 = xr[(size_t)(v3 & 0xffff) * 64 + lane];
        ACC8(v0 >> 16, u0);
        ACC8(v1 >> 16, u1);
        ACC8(v2 >> 16, u2);
        ACC8(v3 >> 16, u3);
    }
    for (; j < j1; ++j) {
        int v = __builtin_amdgcn_readfirstlane(rowidx[j]);
        u32 u = xr[(size_t)(v & 0xffff) * 64 + lane];
        ACC8(v >> 16, u);
    }

    // write R planes: s layout [R][N][128] bf16 so the GEMM streams each k-chunk plane
    size_t plane = (size_t)N_ * 64;
    u32* sp = (u32*)s + (size_t)node * 64 + lane;
#pragma unroll
    for (int r = 0; r < 8; ++r)
        if (r < R_) sp[(size_t)r * plane] = pack_bf2(aL[r], aH[r]);
}

// ---- fused GEMM: C[v,:] = sum_{c=0..R-1} s[c][v] @ W_c  +  self[v] @ loopW  (K = (R+1)*128)
// mode 0: += bias, relu, write bf16 (layer-1 h). mode 1: += bias, row-L2-normalize, write out.
// 64x128 tile per block, 4 waves; A staged per 128-k chunk via global_load_lds (XOR swizzle).
__global__ __launch_bounds__(256)
void gemm_fused(const u16* __restrict__ s,
                const u16* __restrict__ selfc, const u16* __restrict__ selfo,
                const u16* __restrict__ Wc, const u16* __restrict__ Wo,
                const u16* __restrict__ lWc, const u16* __restrict__ lWo,
                const u16* __restrict__ bc, const u16* __restrict__ bo,
                const int* __restrict__ flag,
                int M, int R_, int mode, void* __restrict__ out)
{
    __shared__ u16 As[BM * 128];   // 16 KiB
    const bool f = (*flag != 0);
    const u16* self  = f ? selfc : selfo;
    const u16* Wall  = f ? Wc  : Wo;
    const u16* loopW = f ? lWc : lWo;
    const u16* bias  = f ? bc  : bo;

    const int row0 = blockIdx.x * BM;
    const int tid  = threadIdx.x;
    const int lane = tid & 63;
    const int wv   = tid >> 6;
    const int quad = lane >> 4;
    const int l16  = lane & 15;

    f32x4 acc[4][2];
#pragma unroll
    for (int mt = 0; mt < 4; ++mt) { acc[mt][0] = (f32x4)0.f; acc[mt][1] = (f32x4)0.f; }

    const size_t planeE = (size_t)M * D;
    const int r_base = (wv << 2) + (lane >> 4);   // 0..15
    const int ccol   = lane & 15;

    for (int c = 0; c <= R_; ++c) {
        const u16* Ak = (c < R_) ? (s + (size_t)c * planeE) : self;
        const u16* B  = (c < R_) ? (Wall + (size_t)c * D * D) : loopW;

        // stage A chunk: 64 rows x 128 cols bf16, XOR swizzle cg = col16 ^ (row&15)
        {
            auto* lds0 = (__attribute__((address_space(3))) char*)As;
            int cg = ccol ^ r_base;   // rl&15 == r_base for all it
            int rg0 = row0 + r_base;
#pragma unroll
            for (int it = 0; it < 4; ++it) {
                int rg = rg0 + it * 16; if (rg >= M) rg = M - 1;
                const u16* gp = Ak + (size_t)rg * D + cg * 8;
                __builtin_amdgcn_global_load_lds(
                    (const __attribute__((address_space(1))) void*)gp,
                    (__attribute__((address_space(3))) void*)(lds0 + it * 4096 + wv * 1024),
                    16, 0, 0);
            }
        }

        // B fragments for this chunk (L2-hot: 288KB total weights)
        s16x8 bf[4][2];
#pragma unroll
        for (int ks = 0; ks < 4; ++ks)
#pragma unroll
            for (int jj = 0; jj < 8; ++jj) {
                u32 p = *(const u32*)(B + (ks * 32 + quad * 8 + jj) * D + wv * 32 + 2 * l16);
                bf[ks][0][jj] = (short)(p & 0xffffu);
                bf[ks][1][jj] = (short)(p >> 16);
            }

        __syncthreads();   // drains global_load_lds (compiler emits vmcnt(0) before barrier)

#pragma unroll
        for (int ks = 0; ks < 4; ++ks) {
            const int chunk = (ks * 4 + quad) ^ l16;
#pragma unroll
            for (int mt = 0; mt < 4; ++mt) {
                s16x8 a = *(const s16x8*)(As + (mt * 16 + l16) * D + chunk * 8);
                acc[mt][0] = __builtin_amdgcn_mfma_f32_16x16x32_bf16(a, bf[ks][0], acc[mt][0], 0, 0, 0);
                acc[mt][1] = __builtin_amdgcn_mfma_f32_16x16x32_bf16(a, bf[ks][1], acc[mt][1], 0, 0, 0);
            }
        }
        __syncthreads();   // all reads done before next chunk overwrites As
    }

    const int cpair = wv * 16 + l16;
    const float b0 = bf2f(bias[2 * cpair]);
    const float b1 = bf2f(bias[2 * cpair + 1]);

    if (mode == 0) {
        u32* o = (u32*)out;
#pragma unroll
        for (int mt = 0; mt < 4; ++mt)
#pragma unroll
            for (int i = 0; i < 4; ++i) {
                int r = row0 + mt * 16 + quad * 4 + i;
                if (r >= M) continue;
                o[(size_t)r * 64 + cpair] = pack_bf2(fmaxf(acc[mt][0][i] + b0, 0.f),
                                                     fmaxf(acc[mt][1][i] + b1, 0.f));
            }
    } else {
        // row-wise L2 normalize: block owns full 128-wide rows.
        float pr[4][4];
#pragma unroll
        for (int mt = 0; mt < 4; ++mt)
#pragma unroll
            for (int i = 0; i < 4; ++i) {
                float a0 = acc[mt][0][i] + b0;
                float a1 = acc[mt][1][i] + b1;
                acc[mt][0][i] = a0; acc[mt][1][i] = a1;
                float p = a0 * a0 + a1 * a1;
                p += __shfl_xor(p, 1, 64);
                p += __shfl_xor(p, 2, 64);
                p += __shfl_xor(p, 4, 64);
                p += __shfl_xor(p, 8, 64);
                pr[mt][i] = p;   // sum over the 16 lanes of this quad (32 cols)
            }
        float* fs = (float*)As;   // reuse LDS: rowsum[64][4] at fs[0..255], scale at fs[256..319]
        if (l16 == 0) {
#pragma unroll
            for (int mt = 0; mt < 4; ++mt)
#pragma unroll
                for (int i = 0; i < 4; ++i)
                    fs[(mt * 16 + quad * 4 + i) * 4 + wv] = pr[mt][i];
        }
        __syncthreads();
        if (tid < 64) {
            float ssum = fs[tid * 4] + fs[tid * 4 + 1] + fs[tid * 4 + 2] + fs[tid * 4 + 3];
            fs[256 + tid] = 1.f / fmaxf(sqrtf(ssum), 1e-12f);
        }
        __syncthreads();
#pragma unroll
        for (int mt = 0; mt < 4; ++mt)
#pragma unroll
            for (int i = 0; i < 4; ++i) {
                int rl = mt * 16 + quad * 4 + i;
                int r = row0 + rl;
                if (r >= M) continue;
                float sc = fs[256 + rl];
                float a0 = acc[mt][0][i] * sc, a1 = acc[mt][1][i] * sc;
                if (f) {
                    f32x2 w; w[0] = a0; w[1] = a1;
                    ((f32x2*)out)[(size_t)r * 64 + cpair] = w;
                } else {
                    ((u32*)out)[(size_t)r * 64 + cpair] = pack_bf2(a0, a1);
                }
            }
    }
}

static inline size_t align256(size_t x) { return (x + 255) & ~(size_t)255; }

extern "C" void kernel_launch(void* const* d_in, const int* in_sizes, int n_in,
                              void* d_out, int out_size, void* d_ws, size_t ws_size,
                              hipStream_t stream)
{
    const void* x_in   = d_in[0];
    const void* W1_in  = d_in[1];
    const void* lW1_in = d_in[2];
    const void* b1_in  = d_in[3];
    const void* W2_in  = d_in[4];
    const void* lW2_in = d_in[5];
    const void* b2_in  = d_in[6];
    const int* src = (const int*)d_in[7];
    const int* dst = (const int*)d_in[8];
    const int* et  = (const int*)d_in[9];

    const int N = in_sizes[0] / D;            // 50000
    const int E = in_sizes[7];                // 800000
    const int R = in_sizes[1] / (D * D);      // 8
    const int nbuck = (N + 255) >> 8;         // 196

    const long long ND  = (long long)N * D;
    const long long RDD = (long long)R * D * D;
    const long long DDl = (long long)D * D;

    size_t off = 0;
    auto alloc = [&](size_t bytes) { size_t o = off; off = align256(off + bytes); return o; };
    size_t o_flag = alloc(256);
    size_t o_xc   = alloc((size_t)ND * 2);
    size_t o_W1   = alloc((size_t)RDD * 2);
    size_t o_lW1  = alloc((size_t)DDl * 2);
    size_t o_b1   = alloc((size_t)D * 2);
    size_t o_W2   = alloc((size_t)RDD * 2);
    size_t o_lW2  = alloc((size_t)DDl * 2);
    size_t o_b2   = alloc((size_t)D * 2);
    size_t o_h    = alloc((size_t)ND * 2);
    size_t o_offs = alloc((size_t)(N + 1) * 4);
    size_t o_gcnt = alloc(1024);
    size_t o_bst  = alloc(1040 * 4);
    size_t o_bcur = alloc(1024);
    size_t o_ebuf = alloc((size_t)E * 4);
    size_t o_ridx = alloc((size_t)E * 4);
    size_t o_s    = alloc((size_t)R * ND * 2);   // s[R][N][128] bf16
    (void)ws_size;

    char* ws = (char*)d_ws;
    int* flag   = (int*)(ws + o_flag);
    u16* x_c    = (u16*)(ws + o_xc);
    u16* W1c    = (u16*)(ws + o_W1);
    u16* lW1c   = (u16*)(ws + o_lW1);
    u16* b1c    = (u16*)(ws + o_b1);
    u16* W2c    = (u16*)(ws + o_W2);
    u16* lW2c   = (u16*)(ws + o_lW2);
    u16* b2c    = (u16*)(ws + o_b2);
    u16* h      = (u16*)(ws + o_h);
    int* offs   = (int*)(ws + o_offs);
    int* gcnt   = (int*)(ws + o_gcnt);
    int* bstart = (int*)(ws + o_bst);
    int* bcur   = (int*)(ws + o_bcur);
    u32* ebuf   = (u32*)(ws + o_ebuf);
    int* rowidx = (int*)(ws + o_ridx);
    u16* sbuf   = (u16*)(ws + o_s);

    dim3 blk(256, 1, 1);
    int mb    = (N + BM - 1) / BM;            // 782 blocks
    int nblkE = (E + CH - 1) / CH;
    auto cdiv = [](long long n) { return (u32)((n + 255) / 256); };

    detect_dtype<<<dim3(1), blk, 0, stream>>>((const u16*)x_in, flag, gcnt, nbuck);
    long long tot = ND + RDD + DDl + D + RDD + DDl + D;
    to_bf16_all<<<dim3(cdiv(tot)), blk, 0, stream>>>(
        x_in, W1_in, lW1_in, b1_in, W2_in, lW2_in, b2_in,
        x_c, W1c, lW1c, b1c, W2c, lW2c, b2c,
        ND, RDD, DDl, (long long)D, RDD, DDl, (long long)D, flag);

    // CSR build (bucketed counting sort)
    csr_count<<<dim3(nblkE), blk, 0, stream>>>(dst, gcnt, E, nbuck);
    csr_scan<<<dim3(1), blk, 0, stream>>>(gcnt, bstart, bcur, nbuck, N, E, offs);
    csr_part<<<dim3(nblkE), blk, 0, stream>>>(src, dst, et, bcur, ebuf, E, N, nbuck);
    csr_emit<<<dim3(nbuck), blk, 0, stream>>>(ebuf, bstart, offs, rowidx, N);

    // layer 1: aggregate in input space, then one deep GEMM (K=(R+1)*128) with fused bias+relu
    agg_pre<<<dim3((N + 3) / 4), blk, 0, stream>>>(
        x_c, (const u16*)x_in, offs, rowidx, sbuf, N, R, flag);
    gemm_fused<<<dim3(mb), blk, 0, stream>>>(
        sbuf, x_c, (const u16*)x_in, W1c, (const u16*)W1_in, lW1c, (const u16*)lW1_in,
        b1c, (const u16*)b1_in, flag, N, R, 0, h);

    // layer 2: same, fused bias + row-L2-normalize epilogue
    agg_pre<<<dim3((N + 3) / 4), blk, 0, stream>>>(
        h, h, offs, rowidx, sbuf, N, R, flag);
    gemm_fused<<<dim3(mb), blk, 0, stream>>>(
        sbuf, h, h, W2c, (const u16*)W2_in, lW2c, (const u16*)lW2_in,
        b2c, (const u16*)b2_in, flag, N, R, 1, d_out);
}